// Round 11
// baseline (3270.266 us; speedup 1.0000x reference)
//
#include <hip/hip_runtime.h>
#include <hip/hip_bf16.h>
#include <cstdint>

#define A_N   100000   // atoms
#define B_N   200000   // bonds
#define MAXNB 6
#define AFD   133
#define BFD   147
#define HID   512
#define NMOL  8192
#define MAXDEG 32

typedef __attribute__((ext_vector_type(8))) short bf16x8;
typedef __attribute__((ext_vector_type(4))) float f32x4;

__device__ __forceinline__ unsigned short f2b(float f) {
    unsigned u = __builtin_bit_cast(unsigned, f);
    u += 0x7fffu + ((u >> 16) & 1u);
    return (unsigned short)(u >> 16);
}
__device__ __forceinline__ float blo(unsigned u) { return __builtin_bit_cast(float, u << 16); }
__device__ __forceinline__ float bhi(unsigned u) { return __builtin_bit_cast(float, u & 0xffff0000u); }
__device__ __forceinline__ unsigned pack2f(float a, float b) {
    return (unsigned)f2b(a) | ((unsigned)f2b(b) << 16);
}
__device__ __forceinline__ void glds16(const void* g, void* l) {
    __builtin_amdgcn_global_load_lds((const __attribute__((address_space(1))) unsigned*)g,
                                     (__attribute__((address_space(3))) unsigned*)l, 16, 0, 0);
}

// ---------------- diagnostic fallback (ws too small) ----------------
__global__ __launch_bounds__(256) void k_diag(float* __restrict__ out, int n, float val) {
    int i = blockIdx.x * 256 + threadIdx.x;
    if (i < n) out[i] = val;
}

// ---------------- weight transpose + cast ----------------
// WiT[n][k]   : k 0..146 = Wi[k][n], 147..159 = 0                   (512 x 160 row-major)
// WcatImg     : pre-swizzled glds image, 128-row tiles (bn*21+kt) of 4096 ush;
//               logical k: 0..511 Wh, 512..658 Wi, 659.. 0
// WoT[n][k]   : k 0..132 = Wo[k][n], 133..159 = 0, 160..671 = Wo[k-27][n]  (512 x 672 row-major)
__global__ __launch_bounds__(256) void k_weights(
    const float* __restrict__ Wi, const float* __restrict__ Wh, const float* __restrict__ Wo,
    unsigned short* __restrict__ WiT, unsigned short* __restrict__ WcatImg, unsigned short* __restrict__ WoT)
{
    int n = blockIdx.x, t = threadIdx.x;
    for (int k = t; k < 160; k += 256)
        WiT[(size_t)n * 160 + k] = (k < BFD) ? f2b(Wi[(size_t)k * HID + n]) : (unsigned short)0;
    for (int k = t; k < 672; k += 256) {
        unsigned short v;
        if (k < HID)             v = f2b(Wh[(size_t)k * HID + n]);
        else if (k < HID + BFD)  v = f2b(Wi[(size_t)(k - HID) * HID + n]);
        else                     v = 0;
        int row = n & 127;
        size_t tile = (size_t)(n >> 7) * 21 + (k >> 5);
        WcatImg[tile * 4096 + row * 32 + ((((k >> 3) & 3) ^ ((row >> 1) & 3)) << 3) + (k & 7)] = v;
    }
    for (int k = t; k < 672; k += 256) {
        unsigned short v;
        if (k < AFD)       v = f2b(Wo[(size_t)k * HID + n]);
        else if (k < 160)  v = 0;
        else               v = f2b(Wo[(size_t)(k - 27) * HID + n]);
        WoT[(size_t)n * 672 + k] = v;
    }
}

// ---------------- CSR-lite build: slot[a][i] = i-th bond with b2a==a ----------------
__global__ __launch_bounds__(256) void k_zero(int* __restrict__ cnt, int* __restrict__ ovfc) {
    int i = blockIdx.x * 256 + threadIdx.x;
    if (i < A_N) cnt[i] = 0;
    if (i == 0) *ovfc = 0;
}
__global__ __launch_bounds__(256) void k_fill(
    const int* __restrict__ b2a, int* __restrict__ cnt, int* __restrict__ slot,
    int* __restrict__ ovfc, int* __restrict__ ovf)
{
    int b = blockIdx.x * 256 + threadIdx.x;
    if (b >= B_N) return;
    int a = b2a[b];
    int pos = atomicAdd(&cnt[a], 1);
    if (pos < MAXDEG) slot[(size_t)a * MAXDEG + pos] = b;
    else { int o = atomicAdd(ovfc, 1); ovf[o] = b; }
}

// ---------------- delta (atom-major): one wave per atom, sum kept in regs ----------------
__global__ __launch_bounds__(256) void k_delta_atom(
    const unsigned short* __restrict__ msg, const int* __restrict__ a2b,
    const int* __restrict__ b2revb, const int* __restrict__ cnt, const int* __restrict__ slot,
    unsigned short* __restrict__ D)
{
    int a = blockIdx.x * 4 + (threadIdx.x >> 6);
    if (a >= A_N) return;
    int lane = threadIdx.x & 63;
    const int* nb = a2b + (size_t)a * MAXNB;
    float s[8] = {};
#pragma unroll
    for (int k = 0; k < MAXNB; k++) {
        uint4 v = *(const uint4*)(msg + (size_t)nb[k] * HID + lane * 8);
        s[0] += blo(v.x); s[1] += bhi(v.x);
        s[2] += blo(v.y); s[3] += bhi(v.y);
        s[4] += blo(v.z); s[5] += bhi(v.z);
        s[6] += blo(v.w); s[7] += bhi(v.w);
    }
    int deg = min(cnt[a], MAXDEG);
    const int* sl = slot + (size_t)a * MAXDEG;
    for (int i = 0; i < deg; i++) {
        int b = sl[i];
        uint4 vr = *(const uint4*)(msg + (size_t)b2revb[b] * HID + lane * 8);
        uint4 q;
        q.x = pack2f(s[0] - blo(vr.x), s[1] - bhi(vr.x));
        q.y = pack2f(s[2] - blo(vr.y), s[3] - bhi(vr.y));
        q.z = pack2f(s[4] - blo(vr.z), s[5] - bhi(vr.z));
        q.w = pack2f(s[6] - blo(vr.w), s[7] - bhi(vr.w));
        *(uint4*)(D + (size_t)b * HID + lane * 8) = q;
    }
}

// overflow fallback: old per-bond 7-row path for bonds whose atom exceeded MAXDEG
__global__ __launch_bounds__(256) void k_delta_ovf(
    const unsigned short* __restrict__ msg, const int* __restrict__ a2b,
    const int* __restrict__ b2a, const int* __restrict__ b2revb,
    const int* __restrict__ ovfc, const int* __restrict__ ovf,
    unsigned short* __restrict__ D)
{
    int n = *ovfc;
    int lane = threadIdx.x & 63;
    for (int idx = blockIdx.x * 4 + (threadIdx.x >> 6); idx < n; idx += gridDim.x * 4) {
        int b = ovf[idx];
        const int* nbp = a2b + (size_t)b2a[b] * MAXNB;
        float s[8] = {};
#pragma unroll
        for (int k = 0; k < MAXNB; k++) {
            uint4 v = *(const uint4*)(msg + (size_t)nbp[k] * HID + lane * 8);
            s[0] += blo(v.x); s[1] += bhi(v.x);
            s[2] += blo(v.y); s[3] += bhi(v.y);
            s[4] += blo(v.z); s[5] += bhi(v.z);
            s[6] += blo(v.w); s[7] += bhi(v.w);
        }
        uint4 vr = *(const uint4*)(msg + (size_t)b2revb[b] * HID + lane * 8);
        uint4 q;
        q.x = pack2f(s[0] - blo(vr.x), s[1] - bhi(vr.x));
        q.y = pack2f(s[2] - blo(vr.y), s[3] - bhi(vr.y));
        q.z = pack2f(s[4] - blo(vr.z), s[5] - bhi(vr.z));
        q.w = pack2f(s[6] - blo(vr.w), s[7] - bhi(vr.w));
        *(uint4*)(D + (size_t)b * HID + lane * 8) = q;
    }
}

// ---------------- GEMM 1: msg = relu(f_bonds @ W_i) ----------------
__global__ __launch_bounds__(256, 5) void k_gemm_wi(
    const float* __restrict__ fb, const unsigned short* __restrict__ WiT,
    unsigned short* __restrict__ msg)
{
    __shared__ unsigned short As[128][32];
    __shared__ unsigned short Bs[128][32];
    const int orig = blockIdx.x;
    const int xcd = orig & 7, idx = orig >> 3;
    const int wg = (xcd < 4 ? xcd * 782 : 3128 + (xcd - 4) * 781) + idx;
    const int bm = wg >> 2, bn = wg & 3;
    const int row0 = bm * 128, col0 = bn * 128;

    const int tid = threadIdx.x, lane = tid & 63, wid = tid >> 6;
    const int wm = wid >> 1, wn = wid & 1;
    const int r0 = tid >> 2, c0 = tid & 3, r1 = 64 + r0;
    const int wsw = (c0 ^ ((r0 >> 1) & 3)) * 8;
    const int rsw = ((lane >> 4) ^ (((lane & 15) >> 1) & 3)) * 8;
    f32x4 acc[4][4] = {};

    const float* pf0 = fb + (size_t)min(row0 + r0, B_N - 1) * BFD;
    const float* pf1 = fb + (size_t)min(row0 + r1, B_N - 1) * BFD;
    const unsigned short* pb0 = WiT + (size_t)(col0 + r0) * 160;
    const unsigned short* pb1 = WiT + (size_t)(col0 + r1) * 160;

    float v0[8], v1[8];
    uint4 b0, b1;

#define LOADA(kt) do { int kb = (kt) * 32 + c0 * 8; \
        _Pragma("unroll") for (int i = 0; i < 8; i++) { int kg = kb + i; v0[i] = (kg < BFD) ? pf0[kg] : 0.f; } \
        _Pragma("unroll") for (int i = 0; i < 8; i++) { int kg = kb + i; v1[i] = (kg < BFD) ? pf1[kg] : 0.f; } } while (0)
#define LOADB(kt) do { int kb = (kt) * 32 + c0 * 8; \
        b0 = *(const uint4*)(pb0 + kb); b1 = *(const uint4*)(pb1 + kb); } while (0)

    LOADA(0); LOADB(0);
    for (int kt = 0; kt < 5; ++kt) {
        __syncthreads();
        uint4 q;
        q.x = pack2f(v0[0], v0[1]); q.y = pack2f(v0[2], v0[3]); q.z = pack2f(v0[4], v0[5]); q.w = pack2f(v0[6], v0[7]);
        *(uint4*)&As[r0][wsw] = q;
        q.x = pack2f(v1[0], v1[1]); q.y = pack2f(v1[2], v1[3]); q.z = pack2f(v1[4], v1[5]); q.w = pack2f(v1[6], v1[7]);
        *(uint4*)&As[r1][wsw] = q;
        *(uint4*)&Bs[r0][wsw] = b0;
        *(uint4*)&Bs[r1][wsw] = b1;
        __syncthreads();
        if (kt < 4) { LOADA(kt + 1); LOADB(kt + 1); }

        bf16x8 af[4], bfr[4];
#pragma unroll
        for (int m = 0; m < 4; m++) af[m] = *(const bf16x8*)&As[wm * 64 + m * 16 + (lane & 15)][rsw];
#pragma unroll
        for (int n = 0; n < 4; n++) bfr[n] = *(const bf16x8*)&Bs[wn * 64 + n * 16 + (lane & 15)][rsw];
#pragma unroll
        for (int m = 0; m < 4; m++)
#pragma unroll
            for (int n = 0; n < 4; n++)
                acc[m][n] = __builtin_amdgcn_mfma_f32_16x16x32_bf16(af[m], bfr[n], acc[m][n], 0, 0, 0);
    }
#undef LOADA
#undef LOADB

#pragma unroll
    for (int m = 0; m < 4; m++) {
        int rbase = row0 + wm * 64 + m * 16 + (lane >> 4) * 4;
#pragma unroll
        for (int n = 0; n < 4; n++) {
            int cg = col0 + wn * 64 + n * 16 + (lane & 15);
#pragma unroll
            for (int r = 0; r < 4; r++) {
                int rg = rbase + r;
                if (rg < B_N) {
                    float v = acc[m][n][r];
                    msg[(size_t)rg * HID + cg] = f2b(v > 0.f ? v : 0.f);
                }
            }
        }
    }
}

// ---------------- GEMM 2 (hot): msg = relu([D | f_bonds] @ [W_h; W_i]) ----------------
// Round-6 config (best measured): 128x128, 256 threads, 1-deep glds pipeline; 5 blocks/CU.
__global__ __launch_bounds__(256, 5) void k_gemm_wh(
    const unsigned short* __restrict__ D, const float* __restrict__ fb,
    const unsigned short* __restrict__ WcatImg,
    unsigned short* __restrict__ msg_out)
{
    __shared__ unsigned short As[2][128][32];
    __shared__ unsigned short Bs[2][4096];
    const int orig = blockIdx.x;
    const int xcd = orig & 7, idx = orig >> 3;
    const int wg = (xcd < 4 ? xcd * 782 : 3128 + (xcd - 4) * 781) + idx;
    const int bm = wg >> 2, bn = wg & 3;
    const int row0 = bm * 128;

    const int tid = threadIdx.x, lane = tid & 63, wid = tid >> 6;
    const int wm = wid >> 1, wn = wid & 1;
    const int r0 = tid >> 2, c0 = tid & 3, r1 = 64 + r0;
    const int wsw = (c0 ^ ((r0 >> 1) & 3)) * 8;
    const int rsw = ((lane >> 4) ^ (((lane & 15) >> 1) & 3)) * 8;
    f32x4 acc[4][4] = {};

    const int arow1 = wid * 32 + (lane >> 2);
    const int arow2 = arow1 + 16;
    const int achk = lane & 3;
    const unsigned short* srcA1 = D + (size_t)min(row0 + arow1, B_N - 1) * HID + ((achk ^ ((arow1 >> 1) & 3)) << 3);
    const unsigned short* srcA2 = D + (size_t)min(row0 + arow2, B_N - 1) * HID + ((achk ^ ((arow2 >> 1) & 3)) << 3);
    const char* srcB = (const char*)WcatImg + (size_t)bn * 21 * 8192 + wid * 2048 + lane * 16;

    const int rg0 = min(row0 + r0, B_N - 1), rg1 = min(row0 + r1, B_N - 1);
    const float* pf0 = fb + (size_t)rg0 * BFD;
    const float* pf1 = fb + (size_t)rg1 * BFD;
    float v0[8], v1[8];

    // prologue: issue step-0 loads into buf0
    glds16(srcA1, &As[0][wid * 32][0]);
    glds16(srcA2, &As[0][wid * 32 + 16][0]);
    glds16(srcB, &Bs[0][wid * 1024]);
    glds16(srcB + 1024, &Bs[0][wid * 1024 + 512]);

    for (int kt = 0; kt < 21; ++kt) {
        const int cur = kt & 1, nxt = cur ^ 1;
        __syncthreads();   // step-kt loads landed (implicit vmcnt drain); buf[nxt] free
        if (kt >= 16) {
            uint4 q;
            q.x = pack2f(v0[0], v0[1]); q.y = pack2f(v0[2], v0[3]); q.z = pack2f(v0[4], v0[5]); q.w = pack2f(v0[6], v0[7]);
            *(uint4*)&As[cur][r0][wsw] = q;
            q.x = pack2f(v1[0], v1[1]); q.y = pack2f(v1[2], v1[3]); q.z = pack2f(v1[4], v1[5]); q.w = pack2f(v1[6], v1[7]);
            *(uint4*)&As[cur][r1][wsw] = q;
            __syncthreads();   // fb A visible
        }
        if (kt < 20) {
            if (kt + 1 < 16) {
                glds16(srcA1 + (kt + 1) * 32, &As[nxt][wid * 32][0]);
                glds16(srcA2 + (kt + 1) * 32, &As[nxt][wid * 32 + 16][0]);
            }
            glds16(srcB + (size_t)(kt + 1) * 8192, &Bs[nxt][wid * 1024]);
            glds16(srcB + (size_t)(kt + 1) * 8192 + 1024, &Bs[nxt][wid * 1024 + 512]);
        }
        if (kt >= 15 && kt < 20) {   // prefetch fb regs for step kt+1 (overlaps compute)
            int kb = (kt + 1) * 32 - HID + c0 * 8;
#pragma unroll
            for (int i = 0; i < 8; i++) { int kg = kb + i; v0[i] = (kg < BFD) ? pf0[kg] : 0.f; }
#pragma unroll
            for (int i = 0; i < 8; i++) { int kg = kb + i; v1[i] = (kg < BFD) ? pf1[kg] : 0.f; }
        }
        bf16x8 af[4], bfr[4];
#pragma unroll
        for (int m = 0; m < 4; m++) af[m] = *(const bf16x8*)&As[cur][wm * 64 + m * 16 + (lane & 15)][rsw];
#pragma unroll
        for (int n = 0; n < 4; n++) bfr[n] = *(const bf16x8*)&Bs[cur][(wn * 64 + n * 16 + (lane & 15)) * 32 + rsw];
#pragma unroll
        for (int m = 0; m < 4; m++)
#pragma unroll
            for (int n = 0; n < 4; n++)
                acc[m][n] = __builtin_amdgcn_mfma_f32_16x16x32_bf16(af[m], bfr[n], acc[m][n], 0, 0, 0);
    }

#pragma unroll
    for (int m = 0; m < 4; m++) {
        int rbase = row0 + wm * 64 + m * 16 + (lane >> 4) * 4;
#pragma unroll
        for (int n = 0; n < 4; n++) {
            int cg = bn * 128 + wn * 64 + n * 16 + (lane & 15);
#pragma unroll
            for (int r = 0; r < 4; r++) {
                int rg = rbase + r;
                if (rg < B_N) {
                    float v = acc[m][n][r];
                    msg_out[(size_t)rg * HID + cg] = f2b(v > 0.f ? v : 0.f);
                }
            }
        }
    }
}

// ---------------- GEMM 3: atom_hiddens = relu(concat(f_atoms, amsg) @ W_o + b_o) ----------------
__global__ __launch_bounds__(256, 5) void k_gemm_wo(
    const float* __restrict__ fa, const unsigned short* __restrict__ amsg,
    const unsigned short* __restrict__ WoT, const float* __restrict__ bo,
    float* __restrict__ ah)
{
    __shared__ unsigned short As[2][128][32];
    __shared__ unsigned short Bs[2][128][32];
    const int orig = blockIdx.x;
    const int wg = (orig & 7) * 391 + (orig >> 3);   // nwg = 3128 = 8*391
    const int bm = wg >> 2, bn = wg & 3;
    const int row0 = bm * 128, col0 = bn * 128;

    const int tid = threadIdx.x, lane = tid & 63, wid = tid >> 6;
    const int wm = wid >> 1, wn = wid & 1;
    const int r0 = tid >> 2, c0 = tid & 3, r1 = 64 + r0;
    const int wsw = (c0 ^ ((r0 >> 1) & 3)) * 8;
    const int rsw = ((lane >> 4) ^ (((lane & 15) >> 1) & 3)) * 8;
    f32x4 acc[4][4] = {};

    const int grow1 = wid * 32 + (lane >> 2);
    const int grow2 = grow1 + 16;
    const int gchk = lane & 3;
    const int asw1 = (gchk ^ ((grow1 >> 1) & 3)) << 3;
    const int asw2 = (gchk ^ ((grow2 >> 1) & 3)) << 3;
    const unsigned short* srcA1 = amsg + (size_t)min(row0 + grow1, A_N - 1) * HID + asw1 - 160;
    const unsigned short* srcA2 = amsg + (size_t)min(row0 + grow2, A_N - 1) * HID + asw2 - 160;
    const unsigned short* srcB1 = WoT + (size_t)(col0 + grow1) * 672 + asw1;
    const unsigned short* srcB2 = WoT + (size_t)(col0 + grow2) * 672 + asw2;

    const int rg0 = min(row0 + r0, A_N - 1), rg1 = min(row0 + r1, A_N - 1);
    const float* pf0 = fa + (size_t)rg0 * AFD;
    const float* pf1 = fa + (size_t)rg1 * AFD;
    float v0[8], v1[8];

    {
        int kb = c0 * 8;
#pragma unroll
        for (int i = 0; i < 8; i++) { int kg = kb + i; v0[i] = (kg < AFD) ? pf0[kg] : 0.f; }
#pragma unroll
        for (int i = 0; i < 8; i++) { int kg = kb + i; v1[i] = (kg < AFD) ? pf1[kg] : 0.f; }
    }
    glds16(srcB1, &Bs[0][wid * 32][0]);
    glds16(srcB2, &Bs[0][wid * 32 + 16][0]);

    for (int kt = 0; kt < 21; ++kt) {
        const int cur = kt & 1, nxt = cur ^ 1;
        __syncthreads();
        if (kt < 5) {
            uint4 q;
            q.x = pack2f(v0[0], v0[1]); q.y = pack2f(v0[2], v0[3]); q.z = pack2f(v0[4], v0[5]); q.w = pack2f(v0[6], v0[7]);
            *(uint4*)&As[cur][r0][wsw] = q;
            q.x = pack2f(v1[0], v1[1]); q.y = pack2f(v1[2], v1[3]); q.z = pack2f(v1[4], v1[5]); q.w = pack2f(v1[6], v1[7]);
            *(uint4*)&As[cur][r1][wsw] = q;
            __syncthreads();
        }
        if (kt < 20) {
            if (kt + 1 >= 5) {
                glds16(srcA1 + (kt + 1) * 32, &As[nxt][wid * 32][0]);
                glds16(srcA2 + (kt + 1) * 32, &As[nxt][wid * 32 + 16][0]);
            }
            glds16(srcB1 + (kt + 1) * 32, &Bs[nxt][wid * 32][0]);
            glds16(srcB2 + (kt + 1) * 32, &Bs[nxt][wid * 32 + 16][0]);
        }
        if (kt < 4) {
            int kb = (kt + 1) * 32 + c0 * 8;
#pragma unroll
            for (int i = 0; i < 8; i++) { int kg = kb + i; v0[i] = (kg < AFD) ? pf0[kg] : 0.f; }
#pragma unroll
            for (int i = 0; i < 8; i++) { int kg = kb + i; v1[i] = (kg < AFD) ? pf1[kg] : 0.f; }
        }
        bf16x8 af[4], bfr[4];
#pragma unroll
        for (int m = 0; m < 4; m++) af[m] = *(const bf16x8*)&As[cur][wm * 64 + m * 16 + (lane & 15)][rsw];
#pragma unroll
        for (int n = 0; n < 4; n++) bfr[n] = *(const bf16x8*)&Bs[cur][wn * 64 + n * 16 + (lane & 15)][rsw];
#pragma unroll
        for (int m = 0; m < 4; m++)
#pragma unroll
            for (int n = 0; n < 4; n++)
                acc[m][n] = __builtin_amdgcn_mfma_f32_16x16x32_bf16(af[m], bfr[n], acc[m][n], 0, 0, 0);
    }

#pragma unroll
    for (int m = 0; m < 4; m++) {
        int rbase = row0 + wm * 64 + m * 16 + (lane >> 4) * 4;
#pragma unroll
        for (int n = 0; n < 4; n++) {
            int cg = col0 + wn * 64 + n * 16 + (lane & 15);
            float bias = bo[cg];
#pragma unroll
            for (int r = 0; r < 4; r++) {
                int rg = rbase + r;
                if (rg < A_N) {
                    float v = acc[m][n][r] + bias;
                    ah[(size_t)rg * HID + cg] = v > 0.f ? v : 0.f;
                }
            }
        }
    }
}

// ---------------- final gather-sum: amsg[a] = sum_k msg[a2b[a][k]] ; 2 atoms/wave ----------------
__global__ __launch_bounds__(256) void k_gather(
    const unsigned short* __restrict__ msg, const int* __restrict__ a2b,
    unsigned short* __restrict__ amsg)
{
    const int base = blockIdx.x * 8 + ((threadIdx.x >> 6) << 1);   // grid 12500 * 8 = 100000
    const int lane = threadIdx.x & 63;
    const int* nbA = a2b + (size_t)base * MAXNB;
    const int* nbB = a2b + (size_t)(base + 1) * MAXNB;
    uint4 ga[6], gb[6];
#pragma unroll
    for (int k = 0; k < 6; k++) ga[k] = *(const uint4*)(msg + (size_t)nbA[k] * HID + lane * 8);
#pragma unroll
    for (int k = 0; k < 6; k++) gb[k] = *(const uint4*)(msg + (size_t)nbB[k] * HID + lane * 8);

#define SUM6(g, out) do { \
        float s[8]; \
        s[0] = blo(g[0].x)+blo(g[1].x)+blo(g[2].x)+blo(g[3].x)+blo(g[4].x)+blo(g[5].x); \
        s[1] = bhi(g[0].x)+bhi(g[1].x)+bhi(g[2].x)+bhi(g[3].x)+bhi(g[4].x)+bhi(g[5].x); \
        s[2] = blo(g[0].y)+blo(g[1].y)+blo(g[2].y)+blo(g[3].y)+blo(g[4].y)+blo(g[5].y); \
        s[3] = bhi(g[0].y)+bhi(g[1].y)+bhi(g[2].y)+bhi(g[3].y)+bhi(g[4].y)+bhi(g[5].y); \
        s[4] = blo(g[0].z)+blo(g[1].z)+blo(g[2].z)+blo(g[3].z)+blo(g[4].z)+blo(g[5].z); \
        s[5] = bhi(g[0].z)+bhi(g[1].z)+bhi(g[2].z)+bhi(g[3].z)+bhi(g[4].z)+bhi(g[5].z); \
        s[6] = blo(g[0].w)+blo(g[1].w)+blo(g[2].w)+blo(g[3].w)+blo(g[4].w)+blo(g[5].w); \
        s[7] = bhi(g[0].w)+bhi(g[1].w)+bhi(g[2].w)+bhi(g[3].w)+bhi(g[4].w)+bhi(g[5].w); \
        out.x = pack2f(s[0], s[1]); out.y = pack2f(s[2], s[3]); \
        out.z = pack2f(s[4], s[5]); out.w = pack2f(s[6], s[7]); } while (0)

    uint4 qa, qb;
    SUM6(ga, qa);
    SUM6(gb, qb);
    *(uint4*)(amsg + (size_t)base * HID + lane * 8) = qa;
    *(uint4*)(amsg + (size_t)(base + 1) * HID + lane * 8) = qb;
#undef SUM6
}

// ---------------- per-molecule mean (atom_to_mol is sorted) ----------------
__global__ __launch_bounds__(256) void k_segmean(
    const float* __restrict__ ah, const int* __restrict__ a2m, float* __restrict__ out)
{
    int mol = blockIdx.x, t = threadIdx.x;
    int lo, hi;
    { int l = 0, r = A_N; while (l < r) { int m = (l + r) >> 1; if (a2m[m] < mol) l = m + 1; else r = m; } lo = l; }
    { int l = lo, r = A_N; while (l < r) { int m = (l + r) >> 1; if (a2m[m] < mol + 1) l = m + 1; else r = m; } hi = l; }
    float s0 = 0.f, s1 = 0.f;
    for (int a = lo; a < hi; a++) {
        s0 += ah[(size_t)a * HID + t];
        s1 += ah[(size_t)a * HID + 256 + t];
    }
    int c = hi - lo;
    float inv = c > 0 ? 1.0f / (float)c : 0.f;
    out[(size_t)mol * HID + t] = s0 * inv;
    out[(size_t)mol * HID + 256 + t] = s1 * inv;
}

extern "C" void kernel_launch(void* const* d_in, const int* in_sizes, int n_in,
                              void* d_out, int out_size, void* d_ws, size_t ws_size,
                              hipStream_t stream)
{
    const float* f_atoms = (const float*)d_in[0];
    const float* f_bonds = (const float*)d_in[1];
    const float* W_i     = (const float*)d_in[2];
    const float* W_h     = (const float*)d_in[3];
    const float* W_o     = (const float*)d_in[4];
    const float* b_o     = (const float*)d_in[5];
    const int*   a2b     = (const int*)d_in[6];
    const int*   b2a     = (const int*)d_in[7];
    const int*   b2revb  = (const int*)d_in[8];
    const int*   a2m     = (const int*)d_in[9];

    const size_t OFF_MSG  = 0;              // bf16 [B,H] ; later f32 ah [A,H]
    const size_t OFF_D    = 204800000;      // bf16 [B,H] ; later bf16 amsg [A,H]
    const size_t OFF_WIT  = 409600000;      // 163,840
    const size_t OFF_WCAT = 409763840;      // 688,128 (pre-swizzled 128-row image)
    const size_t OFF_WOT  = 410451968;      // 688,128
    const size_t OFF_CNT  = 411140096;      // 100,000 * 4 = 400,000
    const size_t OFF_SLOT = 411540096;      // 100,000 * 32 * 4 = 12,800,000
    const size_t OFF_OVFC = 424340096;      // 64
    const size_t OFF_OVF  = 424340160;      // 200,000 * 4 = 800,000 (worst case)
    const size_t REQUIRED = 425140160;

    if (ws_size < REQUIRED) {
        float val = -(10000.0f + (float)(ws_size >> 20));
        k_diag<<<dim3((out_size + 255) / 256), dim3(256), 0, stream>>>((float*)d_out, out_size, val);
        return;
    }

    char* w = (char*)d_ws;
    unsigned short* msg   = (unsigned short*)(w + OFF_MSG);
    unsigned short* D     = (unsigned short*)(w + OFF_D);
    unsigned short* amsg  = (unsigned short*)(w + OFF_D);   // aliases D (dead after loop)
    unsigned short* WiT   = (unsigned short*)(w + OFF_WIT);
    unsigned short* Wcat  = (unsigned short*)(w + OFF_WCAT);
    unsigned short* WoT   = (unsigned short*)(w + OFF_WOT);
    int* cnt              = (int*)(w + OFF_CNT);
    int* slot             = (int*)(w + OFF_SLOT);
    int* ovfc             = (int*)(w + OFF_OVFC);
    int* ovf              = (int*)(w + OFF_OVF);
    float* ah             = (float*)(w + OFF_MSG);          // aliases msg (dead after gather)

    k_weights<<<dim3(512), dim3(256), 0, stream>>>(W_i, W_h, W_o, WiT, Wcat, WoT);
    k_zero<<<dim3(391), dim3(256), 0, stream>>>(cnt, ovfc);
    k_fill<<<dim3(782), dim3(256), 0, stream>>>(b2a, cnt, slot, ovfc, ovf);
    k_gemm_wi<<<dim3(6252), dim3(256), 0, stream>>>(f_bonds, WiT, msg);
    for (int it = 0; it < 4; ++it) {
        k_delta_atom<<<dim3(25000), dim3(256), 0, stream>>>(msg, a2b, b2revb, cnt, slot, D);
        k_delta_ovf<<<dim3(64), dim3(256), 0, stream>>>(msg, a2b, b2a, b2revb, ovfc, ovf, D);
        k_gemm_wh<<<dim3(6252), dim3(256), 0, stream>>>(D, f_bonds, Wcat, msg);
    }
    k_gather<<<dim3(12500), dim3(256), 0, stream>>>(msg, a2b, amsg);
    k_gemm_wo<<<dim3(3128), dim3(256), 0, stream>>>(f_atoms, amsg, WoT, b_o, ah);
    k_segmean<<<dim3(NMOL), dim3(256), 0, stream>>>(ah, a2m, (float*)d_out);
}

// Round 12
// 2049.273 us; speedup vs baseline: 1.5958x; 1.5958x over previous
//
#include <hip/hip_runtime.h>
#include <hip/hip_bf16.h>
#include <cstdint>

#define A_N   100000   // atoms
#define B_N   200000   // bonds
#define MAXNB 6
#define AFD   133
#define BFD   147
#define HID   512
#define NMOL  8192
#define MAXDEG 32

typedef __attribute__((ext_vector_type(8))) short bf16x8;
typedef __attribute__((ext_vector_type(4))) float f32x4;

__device__ __forceinline__ unsigned short f2b(float f) {
    unsigned u = __builtin_bit_cast(unsigned, f);
    u += 0x7fffu + ((u >> 16) & 1u);
    return (unsigned short)(u >> 16);
}
__device__ __forceinline__ float blo(unsigned u) { return __builtin_bit_cast(float, u << 16); }
__device__ __forceinline__ float bhi(unsigned u) { return __builtin_bit_cast(float, u & 0xffff0000u); }
__device__ __forceinline__ unsigned pack2f(float a, float b) {
    return (unsigned)f2b(a) | ((unsigned)f2b(b) << 16);
}
__device__ __forceinline__ void glds16(const void* g, void* l) {
    __builtin_amdgcn_global_load_lds((const __attribute__((address_space(1))) unsigned*)g,
                                     (__attribute__((address_space(3))) unsigned*)l, 16, 0, 0);
}

// ---------------- diagnostic fallback (ws too small) ----------------
__global__ __launch_bounds__(256) void k_diag(float* __restrict__ out, int n, float val) {
    int i = blockIdx.x * 256 + threadIdx.x;
    if (i < n) out[i] = val;
}

// ---------------- weight transpose + cast ----------------
// WiT[n][k]   : k 0..146 = Wi[k][n], 147..159 = 0                   (512 x 160 row-major)
// WcatImg     : pre-swizzled glds image, 128-row tiles (bn*21+kt) of 4096 ush;
//               logical k: 0..511 Wh, 512..658 Wi, 659.. 0
// WoT[n][k]   : k 0..132 = Wo[k][n], 133..159 = 0, 160..671 = Wo[k-27][n]  (512 x 672 row-major)
__global__ __launch_bounds__(256) void k_weights(
    const float* __restrict__ Wi, const float* __restrict__ Wh, const float* __restrict__ Wo,
    unsigned short* __restrict__ WiT, unsigned short* __restrict__ WcatImg, unsigned short* __restrict__ WoT)
{
    int n = blockIdx.x, t = threadIdx.x;
    for (int k = t; k < 160; k += 256)
        WiT[(size_t)n * 160 + k] = (k < BFD) ? f2b(Wi[(size_t)k * HID + n]) : (unsigned short)0;
    for (int k = t; k < 672; k += 256) {
        unsigned short v;
        if (k < HID)             v = f2b(Wh[(size_t)k * HID + n]);
        else if (k < HID + BFD)  v = f2b(Wi[(size_t)(k - HID) * HID + n]);
        else                     v = 0;
        int row = n & 127;
        size_t tile = (size_t)(n >> 7) * 21 + (k >> 5);
        WcatImg[tile * 4096 + row * 32 + ((((k >> 3) & 3) ^ ((row >> 1) & 3)) << 3) + (k & 7)] = v;
    }
    for (int k = t; k < 672; k += 256) {
        unsigned short v;
        if (k < AFD)       v = f2b(Wo[(size_t)k * HID + n]);
        else if (k < 160)  v = 0;
        else               v = f2b(Wo[(size_t)(k - 27) * HID + n]);
        WoT[(size_t)n * 672 + k] = v;
    }
}

// ---------------- CSR-lite build: slot[a][i] = i-th bond with b2a==a ----------------
__global__ __launch_bounds__(256) void k_zero(int* __restrict__ cnt, int* __restrict__ ovfc) {
    int i = blockIdx.x * 256 + threadIdx.x;
    if (i < A_N) cnt[i] = 0;
    if (i == 0) *ovfc = 0;
}
__global__ __launch_bounds__(256) void k_fill(
    const int* __restrict__ b2a, int* __restrict__ cnt, int* __restrict__ slot,
    int* __restrict__ ovfc, int* __restrict__ ovf)
{
    int b = blockIdx.x * 256 + threadIdx.x;
    if (b >= B_N) return;
    int a = b2a[b];
    int pos = atomicAdd(&cnt[a], 1);
    if (pos < MAXDEG) slot[(size_t)a * MAXDEG + pos] = b;
    else { int o = atomicAdd(ovfc, 1); ovf[o] = b; }
}

// ---------------- delta (atom-major): one wave per atom, sum kept in regs ----------------
__global__ __launch_bounds__(256) void k_delta_atom(
    const unsigned short* __restrict__ msg, const int* __restrict__ a2b,
    const int* __restrict__ b2revb, const int* __restrict__ cnt, const int* __restrict__ slot,
    unsigned short* __restrict__ D)
{
    int a = blockIdx.x * 4 + (threadIdx.x >> 6);
    if (a >= A_N) return;
    int lane = threadIdx.x & 63;
    const int* nb = a2b + (size_t)a * MAXNB;
    float s[8] = {};
#pragma unroll
    for (int k = 0; k < MAXNB; k++) {
        uint4 v = *(const uint4*)(msg + (size_t)nb[k] * HID + lane * 8);
        s[0] += blo(v.x); s[1] += bhi(v.x);
        s[2] += blo(v.y); s[3] += bhi(v.y);
        s[4] += blo(v.z); s[5] += bhi(v.z);
        s[6] += blo(v.w); s[7] += bhi(v.w);
    }
    int deg = min(cnt[a], MAXDEG);
    const int* sl = slot + (size_t)a * MAXDEG;
    for (int i = 0; i < deg; i++) {
        int b = sl[i];
        uint4 vr = *(const uint4*)(msg + (size_t)b2revb[b] * HID + lane * 8);
        uint4 q;
        q.x = pack2f(s[0] - blo(vr.x), s[1] - bhi(vr.x));
        q.y = pack2f(s[2] - blo(vr.y), s[3] - bhi(vr.y));
        q.z = pack2f(s[4] - blo(vr.z), s[5] - bhi(vr.z));
        q.w = pack2f(s[6] - blo(vr.w), s[7] - bhi(vr.w));
        *(uint4*)(D + (size_t)b * HID + lane * 8) = q;
    }
}

// overflow fallback: old per-bond 7-row path for bonds whose atom exceeded MAXDEG
__global__ __launch_bounds__(256) void k_delta_ovf(
    const unsigned short* __restrict__ msg, const int* __restrict__ a2b,
    const int* __restrict__ b2a, const int* __restrict__ b2revb,
    const int* __restrict__ ovfc, const int* __restrict__ ovf,
    unsigned short* __restrict__ D)
{
    int n = *ovfc;
    int lane = threadIdx.x & 63;
    for (int idx = blockIdx.x * 4 + (threadIdx.x >> 6); idx < n; idx += gridDim.x * 4) {
        int b = ovf[idx];
        const int* nbp = a2b + (size_t)b2a[b] * MAXNB;
        float s[8] = {};
#pragma unroll
        for (int k = 0; k < MAXNB; k++) {
            uint4 v = *(const uint4*)(msg + (size_t)nbp[k] * HID + lane * 8);
            s[0] += blo(v.x); s[1] += bhi(v.x);
            s[2] += blo(v.y); s[3] += bhi(v.y);
            s[4] += blo(v.z); s[5] += bhi(v.z);
            s[6] += blo(v.w); s[7] += bhi(v.w);
        }
        uint4 vr = *(const uint4*)(msg + (size_t)b2revb[b] * HID + lane * 8);
        uint4 q;
        q.x = pack2f(s[0] - blo(vr.x), s[1] - bhi(vr.x));
        q.y = pack2f(s[2] - blo(vr.y), s[3] - bhi(vr.y));
        q.z = pack2f(s[4] - blo(vr.z), s[5] - bhi(vr.z));
        q.w = pack2f(s[6] - blo(vr.w), s[7] - bhi(vr.w));
        *(uint4*)(D + (size_t)b * HID + lane * 8) = q;
    }
}

// ---------------- GEMM 1: msg = relu(f_bonds @ W_i) ----------------
__global__ __launch_bounds__(256) void k_gemm_wi(
    const float* __restrict__ fb, const unsigned short* __restrict__ WiT,
    unsigned short* __restrict__ msg)
{
    __shared__ unsigned short As[128][32];
    __shared__ unsigned short Bs[128][32];
    const int orig = blockIdx.x;
    const int xcd = orig & 7, idx = orig >> 3;
    const int wg = (xcd < 4 ? xcd * 782 : 3128 + (xcd - 4) * 781) + idx;
    const int bm = wg >> 2, bn = wg & 3;
    const int row0 = bm * 128, col0 = bn * 128;

    const int tid = threadIdx.x, lane = tid & 63, wid = tid >> 6;
    const int wm = wid >> 1, wn = wid & 1;
    const int r0 = tid >> 2, c0 = tid & 3, r1 = 64 + r0;
    const int wsw = (c0 ^ ((r0 >> 1) & 3)) * 8;
    const int rsw = ((lane >> 4) ^ (((lane & 15) >> 1) & 3)) * 8;
    f32x4 acc[4][4] = {};

    const float* pf0 = fb + (size_t)min(row0 + r0, B_N - 1) * BFD;
    const float* pf1 = fb + (size_t)min(row0 + r1, B_N - 1) * BFD;
    const unsigned short* pb0 = WiT + (size_t)(col0 + r0) * 160;
    const unsigned short* pb1 = WiT + (size_t)(col0 + r1) * 160;

    float v0[8], v1[8];
    uint4 b0, b1;

#define LOADA(kt) do { int kb = (kt) * 32 + c0 * 8; \
        _Pragma("unroll") for (int i = 0; i < 8; i++) { int kg = kb + i; v0[i] = (kg < BFD) ? pf0[kg] : 0.f; } \
        _Pragma("unroll") for (int i = 0; i < 8; i++) { int kg = kb + i; v1[i] = (kg < BFD) ? pf1[kg] : 0.f; } } while (0)
#define LOADB(kt) do { int kb = (kt) * 32 + c0 * 8; \
        b0 = *(const uint4*)(pb0 + kb); b1 = *(const uint4*)(pb1 + kb); } while (0)

    LOADA(0); LOADB(0);
    for (int kt = 0; kt < 5; ++kt) {
        __syncthreads();
        uint4 q;
        q.x = pack2f(v0[0], v0[1]); q.y = pack2f(v0[2], v0[3]); q.z = pack2f(v0[4], v0[5]); q.w = pack2f(v0[6], v0[7]);
        *(uint4*)&As[r0][wsw] = q;
        q.x = pack2f(v1[0], v1[1]); q.y = pack2f(v1[2], v1[3]); q.z = pack2f(v1[4], v1[5]); q.w = pack2f(v1[6], v1[7]);
        *(uint4*)&As[r1][wsw] = q;
        *(uint4*)&Bs[r0][wsw] = b0;
        *(uint4*)&Bs[r1][wsw] = b1;
        __syncthreads();
        if (kt < 4) { LOADA(kt + 1); LOADB(kt + 1); }

        bf16x8 af[4], bfr[4];
#pragma unroll
        for (int m = 0; m < 4; m++) af[m] = *(const bf16x8*)&As[wm * 64 + m * 16 + (lane & 15)][rsw];
#pragma unroll
        for (int n = 0; n < 4; n++) bfr[n] = *(const bf16x8*)&Bs[wn * 64 + n * 16 + (lane & 15)][rsw];
#pragma unroll
        for (int m = 0; m < 4; m++)
#pragma unroll
            for (int n = 0; n < 4; n++)
                acc[m][n] = __builtin_amdgcn_mfma_f32_16x16x32_bf16(af[m], bfr[n], acc[m][n], 0, 0, 0);
    }
#undef LOADA
#undef LOADB

#pragma unroll
    for (int m = 0; m < 4; m++) {
        int rbase = row0 + wm * 64 + m * 16 + (lane >> 4) * 4;
#pragma unroll
        for (int n = 0; n < 4; n++) {
            int cg = col0 + wn * 64 + n * 16 + (lane & 15);
#pragma unroll
            for (int r = 0; r < 4; r++) {
                int rg = rbase + r;
                if (rg < B_N) {
                    float v = acc[m][n][r];
                    msg[(size_t)rg * HID + cg] = f2b(v > 0.f ? v : 0.f);
                }
            }
        }
    }
}

// ---------------- GEMM 2 (hot): msg = relu([D | f_bonds] @ [W_h; W_i]) ----------------
// Round-6 config (best measured): 128x128, 256 threads, 1-deep glds pipeline.
__global__ __launch_bounds__(256, 4) void k_gemm_wh(
    const unsigned short* __restrict__ D, const float* __restrict__ fb,
    const unsigned short* __restrict__ WcatImg,
    unsigned short* __restrict__ msg_out)
{
    __shared__ unsigned short As[2][128][32];
    __shared__ unsigned short Bs[2][4096];
    const int orig = blockIdx.x;
    const int xcd = orig & 7, idx = orig >> 3;
    const int wg = (xcd < 4 ? xcd * 782 : 3128 + (xcd - 4) * 781) + idx;
    const int bm = wg >> 2, bn = wg & 3;
    const int row0 = bm * 128;

    const int tid = threadIdx.x, lane = tid & 63, wid = tid >> 6;
    const int wm = wid >> 1, wn = wid & 1;
    const int r0 = tid >> 2, c0 = tid & 3, r1 = 64 + r0;
    const int wsw = (c0 ^ ((r0 >> 1) & 3)) * 8;
    const int rsw = ((lane >> 4) ^ (((lane & 15) >> 1) & 3)) * 8;
    f32x4 acc[4][4] = {};

    const int arow1 = wid * 32 + (lane >> 2);
    const int arow2 = arow1 + 16;
    const int achk = lane & 3;
    const unsigned short* srcA1 = D + (size_t)min(row0 + arow1, B_N - 1) * HID + ((achk ^ ((arow1 >> 1) & 3)) << 3);
    const unsigned short* srcA2 = D + (size_t)min(row0 + arow2, B_N - 1) * HID + ((achk ^ ((arow2 >> 1) & 3)) << 3);
    const char* srcB = (const char*)WcatImg + (size_t)bn * 21 * 8192 + wid * 2048 + lane * 16;

    const int rg0 = min(row0 + r0, B_N - 1), rg1 = min(row0 + r1, B_N - 1);
    const float* pf0 = fb + (size_t)rg0 * BFD;
    const float* pf1 = fb + (size_t)rg1 * BFD;
    float v0[8], v1[8];

    // prologue: issue step-0 loads into buf0
    glds16(srcA1, &As[0][wid * 32][0]);
    glds16(srcA2, &As[0][wid * 32 + 16][0]);
    glds16(srcB, &Bs[0][wid * 1024]);
    glds16(srcB + 1024, &Bs[0][wid * 1024 + 512]);

    for (int kt = 0; kt < 21; ++kt) {
        const int cur = kt & 1, nxt = cur ^ 1;
        __syncthreads();   // step-kt loads landed (implicit vmcnt drain); buf[nxt] free
        if (kt >= 16) {
            uint4 q;
            q.x = pack2f(v0[0], v0[1]); q.y = pack2f(v0[2], v0[3]); q.z = pack2f(v0[4], v0[5]); q.w = pack2f(v0[6], v0[7]);
            *(uint4*)&As[cur][r0][wsw] = q;
            q.x = pack2f(v1[0], v1[1]); q.y = pack2f(v1[2], v1[3]); q.z = pack2f(v1[4], v1[5]); q.w = pack2f(v1[6], v1[7]);
            *(uint4*)&As[cur][r1][wsw] = q;
            __syncthreads();   // fb A visible
        }
        if (kt < 20) {
            if (kt + 1 < 16) {
                glds16(srcA1 + (kt + 1) * 32, &As[nxt][wid * 32][0]);
                glds16(srcA2 + (kt + 1) * 32, &As[nxt][wid * 32 + 16][0]);
            }
            glds16(srcB + (size_t)(kt + 1) * 8192, &Bs[nxt][wid * 1024]);
            glds16(srcB + (size_t)(kt + 1) * 8192 + 1024, &Bs[nxt][wid * 1024 + 512]);
        }
        if (kt >= 15 && kt < 20) {   // prefetch fb regs for step kt+1 (overlaps compute)
            int kb = (kt + 1) * 32 - HID + c0 * 8;
#pragma unroll
            for (int i = 0; i < 8; i++) { int kg = kb + i; v0[i] = (kg < BFD) ? pf0[kg] : 0.f; }
#pragma unroll
            for (int i = 0; i < 8; i++) { int kg = kb + i; v1[i] = (kg < BFD) ? pf1[kg] : 0.f; }
        }
        bf16x8 af[4], bfr[4];
#pragma unroll
        for (int m = 0; m < 4; m++) af[m] = *(const bf16x8*)&As[cur][wm * 64 + m * 16 + (lane & 15)][rsw];
#pragma unroll
        for (int n = 0; n < 4; n++) bfr[n] = *(const bf16x8*)&Bs[cur][(wn * 64 + n * 16 + (lane & 15)) * 32 + rsw];
#pragma unroll
        for (int m = 0; m < 4; m++)
#pragma unroll
            for (int n = 0; n < 4; n++)
                acc[m][n] = __builtin_amdgcn_mfma_f32_16x16x32_bf16(af[m], bfr[n], acc[m][n], 0, 0, 0);
    }

#pragma unroll
    for (int m = 0; m < 4; m++) {
        int rbase = row0 + wm * 64 + m * 16 + (lane >> 4) * 4;
#pragma unroll
        for (int n = 0; n < 4; n++) {
            int cg = bn * 128 + wn * 64 + n * 16 + (lane & 15);
#pragma unroll
            for (int r = 0; r < 4; r++) {
                int rg = rbase + r;
                if (rg < B_N) {
                    float v = acc[m][n][r];
                    msg_out[(size_t)rg * HID + cg] = f2b(v > 0.f ? v : 0.f);
                }
            }
        }
    }
}

// ---------------- GEMM 3: atom_hiddens = relu(concat(f_atoms, amsg) @ W_o + b_o) ----------------
__global__ __launch_bounds__(256, 4) void k_gemm_wo(
    const float* __restrict__ fa, const unsigned short* __restrict__ amsg,
    const unsigned short* __restrict__ WoT, const float* __restrict__ bo,
    float* __restrict__ ah)
{
    __shared__ unsigned short As[2][128][32];
    __shared__ unsigned short Bs[2][128][32];
    const int orig = blockIdx.x;
    const int wg = (orig & 7) * 391 + (orig >> 3);   // nwg = 3128 = 8*391
    const int bm = wg >> 2, bn = wg & 3;
    const int row0 = bm * 128, col0 = bn * 128;

    const int tid = threadIdx.x, lane = tid & 63, wid = tid >> 6;
    const int wm = wid >> 1, wn = wid & 1;
    const int r0 = tid >> 2, c0 = tid & 3, r1 = 64 + r0;
    const int wsw = (c0 ^ ((r0 >> 1) & 3)) * 8;
    const int rsw = ((lane >> 4) ^ (((lane & 15) >> 1) & 3)) * 8;
    f32x4 acc[4][4] = {};

    const int grow1 = wid * 32 + (lane >> 2);
    const int grow2 = grow1 + 16;
    const int gchk = lane & 3;
    const int asw1 = (gchk ^ ((grow1 >> 1) & 3)) << 3;
    const int asw2 = (gchk ^ ((grow2 >> 1) & 3)) << 3;
    const unsigned short* srcA1 = amsg + (size_t)min(row0 + grow1, A_N - 1) * HID + asw1 - 160;
    const unsigned short* srcA2 = amsg + (size_t)min(row0 + grow2, A_N - 1) * HID + asw2 - 160;
    const unsigned short* srcB1 = WoT + (size_t)(col0 + grow1) * 672 + asw1;
    const unsigned short* srcB2 = WoT + (size_t)(col0 + grow2) * 672 + asw2;

    const int rg0 = min(row0 + r0, A_N - 1), rg1 = min(row0 + r1, A_N - 1);
    const float* pf0 = fa + (size_t)rg0 * AFD;
    const float* pf1 = fa + (size_t)rg1 * AFD;
    float v0[8], v1[8];

    {
        int kb = c0 * 8;
#pragma unroll
        for (int i = 0; i < 8; i++) { int kg = kb + i; v0[i] = (kg < AFD) ? pf0[kg] : 0.f; }
#pragma unroll
        for (int i = 0; i < 8; i++) { int kg = kb + i; v1[i] = (kg < AFD) ? pf1[kg] : 0.f; }
    }
    glds16(srcB1, &Bs[0][wid * 32][0]);
    glds16(srcB2, &Bs[0][wid * 32 + 16][0]);

    for (int kt = 0; kt < 21; ++kt) {
        const int cur = kt & 1, nxt = cur ^ 1;
        __syncthreads();
        if (kt < 5) {
            uint4 q;
            q.x = pack2f(v0[0], v0[1]); q.y = pack2f(v0[2], v0[3]); q.z = pack2f(v0[4], v0[5]); q.w = pack2f(v0[6], v0[7]);
            *(uint4*)&As[cur][r0][wsw] = q;
            q.x = pack2f(v1[0], v1[1]); q.y = pack2f(v1[2], v1[3]); q.z = pack2f(v1[4], v1[5]); q.w = pack2f(v1[6], v1[7]);
            *(uint4*)&As[cur][r1][wsw] = q;
            __syncthreads();
        }
        if (kt < 20) {
            if (kt + 1 >= 5) {
                glds16(srcA1 + (kt + 1) * 32, &As[nxt][wid * 32][0]);
                glds16(srcA2 + (kt + 1) * 32, &As[nxt][wid * 32 + 16][0]);
            }
            glds16(srcB1 + (kt + 1) * 32, &Bs[nxt][wid * 32][0]);
            glds16(srcB2 + (kt + 1) * 32, &Bs[nxt][wid * 32 + 16][0]);
        }
        if (kt < 4) {
            int kb = (kt + 1) * 32 + c0 * 8;
#pragma unroll
            for (int i = 0; i < 8; i++) { int kg = kb + i; v0[i] = (kg < AFD) ? pf0[kg] : 0.f; }
#pragma unroll
            for (int i = 0; i < 8; i++) { int kg = kb + i; v1[i] = (kg < AFD) ? pf1[kg] : 0.f; }
        }
        bf16x8 af[4], bfr[4];
#pragma unroll
        for (int m = 0; m < 4; m++) af[m] = *(const bf16x8*)&As[cur][wm * 64 + m * 16 + (lane & 15)][rsw];
#pragma unroll
        for (int n = 0; n < 4; n++) bfr[n] = *(const bf16x8*)&Bs[cur][wn * 64 + n * 16 + (lane & 15)][rsw];
#pragma unroll
        for (int m = 0; m < 4; m++)
#pragma unroll
            for (int n = 0; n < 4; n++)
                acc[m][n] = __builtin_amdgcn_mfma_f32_16x16x32_bf16(af[m], bfr[n], acc[m][n], 0, 0, 0);
    }

#pragma unroll
    for (int m = 0; m < 4; m++) {
        int rbase = row0 + wm * 64 + m * 16 + (lane >> 4) * 4;
#pragma unroll
        for (int n = 0; n < 4; n++) {
            int cg = col0 + wn * 64 + n * 16 + (lane & 15);
            float bias = bo[cg];
#pragma unroll
            for (int r = 0; r < 4; r++) {
                int rg = rbase + r;
                if (rg < A_N) {
                    float v = acc[m][n][r] + bias;
                    ah[(size_t)rg * HID + cg] = v > 0.f ? v : 0.f;
                }
            }
        }
    }
}

// ---------------- final gather-sum: amsg[a] = sum_k msg[a2b[a][k]] ; 2 atoms/wave ----------------
__global__ __launch_bounds__(256) void k_gather(
    const unsigned short* __restrict__ msg, const int* __restrict__ a2b,
    unsigned short* __restrict__ amsg)
{
    const int base = blockIdx.x * 8 + ((threadIdx.x >> 6) << 1);   // grid 12500 * 8 = 100000
    const int lane = threadIdx.x & 63;
    const int* nbA = a2b + (size_t)base * MAXNB;
    const int* nbB = a2b + (size_t)(base + 1) * MAXNB;
    uint4 ga[6], gb[6];
#pragma unroll
    for (int k = 0; k < 6; k++) ga[k] = *(const uint4*)(msg + (size_t)nbA[k] * HID + lane * 8);
#pragma unroll
    for (int k = 0; k < 6; k++) gb[k] = *(const uint4*)(msg + (size_t)nbB[k] * HID + lane * 8);

#define SUM6(g, out) do { \
        float s[8]; \
        s[0] = blo(g[0].x)+blo(g[1].x)+blo(g[2].x)+blo(g[3].x)+blo(g[4].x)+blo(g[5].x); \
        s[1] = bhi(g[0].x)+bhi(g[1].x)+bhi(g[2].x)+bhi(g[3].x)+bhi(g[4].x)+bhi(g[5].x); \
        s[2] = blo(g[0].y)+blo(g[1].y)+blo(g[2].y)+blo(g[3].y)+blo(g[4].y)+blo(g[5].y); \
        s[3] = bhi(g[0].y)+bhi(g[1].y)+bhi(g[2].y)+bhi(g[3].y)+bhi(g[4].y)+bhi(g[5].y); \
        s[4] = blo(g[0].z)+blo(g[1].z)+blo(g[2].z)+blo(g[3].z)+blo(g[4].z)+blo(g[5].z); \
        s[5] = bhi(g[0].z)+bhi(g[1].z)+bhi(g[2].z)+bhi(g[3].z)+bhi(g[4].z)+bhi(g[5].z); \
        s[6] = blo(g[0].w)+blo(g[1].w)+blo(g[2].w)+blo(g[3].w)+blo(g[4].w)+blo(g[5].w); \
        s[7] = bhi(g[0].w)+bhi(g[1].w)+bhi(g[2].w)+bhi(g[3].w)+bhi(g[4].w)+bhi(g[5].w); \
        out.x = pack2f(s[0], s[1]); out.y = pack2f(s[2], s[3]); \
        out.z = pack2f(s[4], s[5]); out.w = pack2f(s[6], s[7]); } while (0)

    uint4 qa, qb;
    SUM6(ga, qa);
    SUM6(gb, qb);
    *(uint4*)(amsg + (size_t)base * HID + lane * 8) = qa;
    *(uint4*)(amsg + (size_t)(base + 1) * HID + lane * 8) = qb;
#undef SUM6
}

// ---------------- per-molecule mean (atom_to_mol is sorted) ----------------
__global__ __launch_bounds__(256) void k_segmean(
    const float* __restrict__ ah, const int* __restrict__ a2m, float* __restrict__ out)
{
    int mol = blockIdx.x, t = threadIdx.x;
    int lo, hi;
    { int l = 0, r = A_N; while (l < r) { int m = (l + r) >> 1; if (a2m[m] < mol) l = m + 1; else r = m; } lo = l; }
    { int l = lo, r = A_N; while (l < r) { int m = (l + r) >> 1; if (a2m[m] < mol + 1) l = m + 1; else r = m; } hi = l; }
    float s0 = 0.f, s1 = 0.f;
    for (int a = lo; a < hi; a++) {
        s0 += ah[(size_t)a * HID + t];
        s1 += ah[(size_t)a * HID + 256 + t];
    }
    int c = hi - lo;
    float inv = c > 0 ? 1.0f / (float)c : 0.f;
    out[(size_t)mol * HID + t] = s0 * inv;
    out[(size_t)mol * HID + 256 + t] = s1 * inv;
}

extern "C" void kernel_launch(void* const* d_in, const int* in_sizes, int n_in,
                              void* d_out, int out_size, void* d_ws, size_t ws_size,
                              hipStream_t stream)
{
    const float* f_atoms = (const float*)d_in[0];
    const float* f_bonds = (const float*)d_in[1];
    const float* W_i     = (const float*)d_in[2];
    const float* W_h     = (const float*)d_in[3];
    const float* W_o     = (const float*)d_in[4];
    const float* b_o     = (const float*)d_in[5];
    const int*   a2b     = (const int*)d_in[6];
    const int*   b2a     = (const int*)d_in[7];
    const int*   b2revb  = (const int*)d_in[8];
    const int*   a2m     = (const int*)d_in[9];

    const size_t OFF_MSG  = 0;              // bf16 [B,H] ; later f32 ah [A,H]
    const size_t OFF_D    = 204800000;      // bf16 [B,H] ; later bf16 amsg [A,H]
    const size_t OFF_WIT  = 409600000;      // 163,840
    const size_t OFF_WCAT = 409763840;      // 688,128 (pre-swizzled 128-row image)
    const size_t OFF_WOT  = 410451968;      // 688,128
    const size_t OFF_CNT  = 411140096;      // 100,000 * 4 = 400,000
    const size_t OFF_SLOT = 411540096;      // 100,000 * 32 * 4 = 12,800,000
    const size_t OFF_OVFC = 424340096;      // 64
    const size_t OFF_OVF  = 424340160;      // 200,000 * 4 = 800,000 (worst case)
    const size_t REQUIRED = 425140160;

    if (ws_size < REQUIRED) {
        float val = -(10000.0f + (float)(ws_size >> 20));
        k_diag<<<dim3((out_size + 255) / 256), dim3(256), 0, stream>>>((float*)d_out, out_size, val);
        return;
    }

    char* w = (char*)d_ws;
    unsigned short* msg   = (unsigned short*)(w + OFF_MSG);
    unsigned short* D     = (unsigned short*)(w + OFF_D);
    unsigned short* amsg  = (unsigned short*)(w + OFF_D);   // aliases D (dead after loop)
    unsigned short* WiT   = (unsigned short*)(w + OFF_WIT);
    unsigned short* Wcat  = (unsigned short*)(w + OFF_WCAT);
    unsigned short* WoT   = (unsigned short*)(w + OFF_WOT);
    int* cnt              = (int*)(w + OFF_CNT);
    int* slot             = (int*)(w + OFF_SLOT);
    int* ovfc             = (int*)(w + OFF_OVFC);
    int* ovf              = (int*)(w + OFF_OVF);
    float* ah             = (float*)(w + OFF_MSG);          // aliases msg (dead after gather)

    k_weights<<<dim3(512), dim3(256), 0, stream>>>(W_i, W_h, W_o, WiT, Wcat, WoT);
    k_zero<<<dim3(391), dim3(256), 0, stream>>>(cnt, ovfc);
    k_fill<<<dim3(782), dim3(256), 0, stream>>>(b2a, cnt, slot, ovfc, ovf);
    k_gemm_wi<<<dim3(6252), dim3(256), 0, stream>>>(f_bonds, WiT, msg);
    for (int it = 0; it < 4; ++it) {
        k_delta_atom<<<dim3(25000), dim3(256), 0, stream>>>(msg, a2b, b2revb, cnt, slot, D);
        k_delta_ovf<<<dim3(64), dim3(256), 0, stream>>>(msg, a2b, b2a, b2revb, ovfc, ovf, D);
        k_gemm_wh<<<dim3(6252), dim3(256), 0, stream>>>(D, f_bonds, Wcat, msg);
    }
    k_gather<<<dim3(12500), dim3(256), 0, stream>>>(msg, a2b, amsg);
    k_gemm_wo<<<dim3(3128), dim3(256), 0, stream>>>(f_atoms, amsg, WoT, b_o, ah);
    k_segmean<<<dim3(NMOL), dim3(256), 0, stream>>>(ah, a2m, (float*)d_out);
}